// Round 4
// baseline (257.356 us; speedup 1.0000x reference)
//
#include <hip/hip_runtime.h>
#include <math.h>

#define BB 2
#define NN 4096
#define DIM 768
#define QSTRIDE 20  // 8 (q head0) + 8 (q head1) + w0 + w1 + 2 pad, float4-aligned

// ---------------------------------------------------------------------------
// qproj: qw = query_tokens @ Wq  (8192 rows x 768 -> 18 cols)
// One wave handles 2 rows. Lane-parallel over the 768 dim, butterfly reduce.
// Output layout per row (stride 20): [q0(8), q1(8), w0, w1, pad(2)]
//   qw cols: head0 q = 0..7, head0 w = 8, head1 q = 9..16, head1 w = 17
// (R0-proven structure: separate kernels; merged-proj correlated with a
//  ~8us regression in R2/R3, reverted.)
// ---------------------------------------------------------------------------
__global__ __launch_bounds__(256) void qproj_kernel(const float* __restrict__ x,
                                                    const float* __restrict__ Wq,
                                                    float* __restrict__ qd) {
  const int lane = threadIdx.x & 63;
  const int pair = blockIdx.x * 4 + (threadIdx.x >> 6);
  const int row0 = pair * 2;
  const float* xr0 = x + (size_t)row0 * DIM;
  const float* xr1 = xr0 + DIM;

  float acc0[18], acc1[18];
#pragma unroll
  for (int c = 0; c < 18; ++c) { acc0[c] = 0.f; acc1[c] = 0.f; }

#pragma unroll
  for (int j = 0; j < DIM / 64; ++j) {
    const int i = lane + 64 * j;
    const float x0 = xr0[i];
    const float x1 = xr1[i];
    const float* wr = Wq + i * 18;
#pragma unroll
    for (int c = 0; c < 9; ++c) {
      const float2 w2 = *(const float2*)(wr + 2 * c);
      acc0[2 * c]     = fmaf(x0, w2.x, acc0[2 * c]);
      acc0[2 * c + 1] = fmaf(x0, w2.y, acc0[2 * c + 1]);
      acc1[2 * c]     = fmaf(x1, w2.x, acc1[2 * c]);
      acc1[2 * c + 1] = fmaf(x1, w2.y, acc1[2 * c + 1]);
    }
  }

#pragma unroll
  for (int off = 32; off >= 1; off >>= 1) {
#pragma unroll
    for (int c = 0; c < 18; ++c) {
      acc0[c] += __shfl_xor(acc0[c], off, 64);
      acc1[c] += __shfl_xor(acc1[c], off, 64);
    }
  }

  // lanes 0..17 write row0, lanes 32..49 write row1 (all lanes hold full sums)
  const int r = lane >> 5;
  const int l = lane & 31;
  if (l < 18) {
    // dst slot l maps to qw column:
    //   l<8 -> col l ; 8<=l<16 -> col l+1 ; l==16 -> col 8 ; l==17 -> col 17
    int src;
    if (l < 8) src = l;
    else if (l < 16) src = l + 1;
    else if (l == 16) src = 8;
    else src = 17;
    float v = r ? acc1[0] : acc0[0];
#pragma unroll
    for (int c = 1; c < 18; ++c) {
      const float cand = r ? acc1[c] : acc0[c];
      v = (src == c) ? cand : v;
    }
    qd[(size_t)(row0 + r) * QSTRIDE + l] = v;
  }
}

// ---------------------------------------------------------------------------
// kproj: k = key_tokens @ Wk (8192 x 768 -> 8) + 2D sinusoidal PE
// pe[n] = [sin(y*h), cos(y*h), sin(y*.01h), cos(y*.01h),
//          sin(x*w), cos(x*w), sin(x*.01w), cos(x*.01w)]
//   y = (n/w_) / max(h-1,1), x = (n%w_) / max(w_-1,1); freqs = [1, 0.01]
// ---------------------------------------------------------------------------
__global__ __launch_bounds__(256) void kproj_kernel(const float* __restrict__ x,
                                                    const float* __restrict__ Wk,
                                                    const int* __restrict__ hp,
                                                    const int* __restrict__ wp,
                                                    float* __restrict__ kd) {
  const int lane = threadIdx.x & 63;
  const int pair = blockIdx.x * 4 + (threadIdx.x >> 6);
  const int row0 = pair * 2;
  const float* xr0 = x + (size_t)row0 * DIM;
  const float* xr1 = xr0 + DIM;

  float acc0[8], acc1[8];
#pragma unroll
  for (int c = 0; c < 8; ++c) { acc0[c] = 0.f; acc1[c] = 0.f; }

#pragma unroll
  for (int j = 0; j < DIM / 64; ++j) {
    const int i = lane + 64 * j;
    const float x0 = xr0[i];
    const float x1 = xr1[i];
    const float4 wa = *(const float4*)(Wk + i * 8);
    const float4 wb = *(const float4*)(Wk + i * 8 + 4);
    acc0[0] = fmaf(x0, wa.x, acc0[0]); acc0[1] = fmaf(x0, wa.y, acc0[1]);
    acc0[2] = fmaf(x0, wa.z, acc0[2]); acc0[3] = fmaf(x0, wa.w, acc0[3]);
    acc0[4] = fmaf(x0, wb.x, acc0[4]); acc0[5] = fmaf(x0, wb.y, acc0[5]);
    acc0[6] = fmaf(x0, wb.z, acc0[6]); acc0[7] = fmaf(x0, wb.w, acc0[7]);
    acc1[0] = fmaf(x1, wa.x, acc1[0]); acc1[1] = fmaf(x1, wa.y, acc1[1]);
    acc1[2] = fmaf(x1, wa.z, acc1[2]); acc1[3] = fmaf(x1, wa.w, acc1[3]);
    acc1[4] = fmaf(x1, wb.x, acc1[4]); acc1[5] = fmaf(x1, wb.y, acc1[5]);
    acc1[6] = fmaf(x1, wb.z, acc1[6]); acc1[7] = fmaf(x1, wb.w, acc1[7]);
  }

#pragma unroll
  for (int off = 32; off >= 1; off >>= 1) {
#pragma unroll
    for (int c = 0; c < 8; ++c) {
      acc0[c] += __shfl_xor(acc0[c], off, 64);
      acc1[c] += __shfl_xor(acc1[c], off, 64);
    }
  }

  const int r = lane >> 5;
  const int l = lane & 31;
  if (l < 8) {
    const int row = row0 + r;
    const int h = hp[0];
    const int w = wp[0];
    const int n = row % NN;
    const int yi = n / w;
    const int xi = n - yi * w;
    const int hd = (h - 1) > 1 ? (h - 1) : 1;
    const int wd = (w - 1) > 1 ? (w - 1) : 1;
    const float yv = (float)yi / (float)hd;
    const float xv = (float)xi / (float)wd;
    const float base = (l < 4) ? yv : xv;
    const float sc = (l < 4) ? (float)h : (float)w;
    const float fr = (l & 2) ? 0.01f : 1.0f;
    const float ang = base * fr * sc;
    const float pe = (l & 1) ? cosf(ang) : sinf(ang);
    float v = r ? acc1[0] : acc0[0];
#pragma unroll
    for (int c = 1; c < 8; ++c) {
      const float cand = r ? acc1[c] : acc0[c];
      v = (l == c) ? cand : v;
    }
    kd[(size_t)row * 8 + l] = v + pe;
  }
}

// ---------------------------------------------------------------------------
// scores: out[b,q,k] = w0*relu(scale*<q0,k>) + w1*relu(scale*<q1,k>) + bias
// Block: 256 threads; tile 32 queries x 64 keys (R0-proven geometry).
// NO LDS staging (Common-mistake #7): kd is 256 KB and qd 640 KB -> both
// fully L2-resident after the proj kernels. kv loads are 16-lane x 16 B
// contiguous (2 KB segments, L1/L2 hits); q loads are same-address
// broadcasts within each 16-lane tx-group (HW broadcast, L1-cached across
// kb blocks). Removes 128 staged float4s + __syncthreads (full waitcnt
// drain) + 288 ds_reads per block; kernel is barrier-free.
// Thread (tx=tid&15, ty=tid>>4): 2 queries x 4 keys -> 2 float4 stores
// (16 lanes x 16 B = 256 B contiguous per instruction per tx-group).
// ---------------------------------------------------------------------------
__device__ __forceinline__ float dot8(const float4 a, const float4 b,
                                      const float4 ka, const float4 kb) {
  float d = a.x * ka.x;
  d = fmaf(a.y, ka.y, d);
  d = fmaf(a.z, ka.z, d);
  d = fmaf(a.w, ka.w, d);
  d = fmaf(b.x, kb.x, d);
  d = fmaf(b.y, kb.y, d);
  d = fmaf(b.z, kb.z, d);
  d = fmaf(b.w, kb.w, d);
  return d;
}

__global__ __launch_bounds__(256) void scores_kernel(const float* __restrict__ qd,
                                                     const float* __restrict__ kd,
                                                     const float* __restrict__ bias,
                                                     float* __restrict__ out) {
  const int tid = threadIdx.x;
  const int kb = blockIdx.x;  // 64-key tile
  const int qb = blockIdx.y;  // 32-query tile
  const int b  = blockIdx.z;

  const int tx = tid & 15;
  const int ty = tid >> 4;
  const float sb = bias[0];
  const float scale = 0.35355339059327373f;  // 8^-0.5

  // kv: thread owns keys k0..k0+3, loaded directly (L2-resident kd)
  const int k0 = tx * 4;
  const float4* kp = (const float4*)(kd + ((size_t)b * NN + kb * 64 + k0) * 8);
  float4 kva[4], kvb[4];
#pragma unroll
  for (int i = 0; i < 4; ++i) {
    kva[i] = kp[2 * i];
    kvb[i] = kp[2 * i + 1];
  }

#pragma unroll
  for (int qi = 0; qi < 2; ++qi) {
    const int lq = ty * 2 + qi;
    const float* qp = qd + ((size_t)b * NN + qb * 32 + lq) * QSTRIDE;
    const float4 a0 = *(const float4*)(qp);
    const float4 a1 = *(const float4*)(qp + 4);
    const float4 b0 = *(const float4*)(qp + 8);
    const float4 b1 = *(const float4*)(qp + 12);
    const float w0 = qp[16];
    const float w1 = qp[17];

    float4 res;
    float* r = (float*)&res;
#pragma unroll
    for (int i = 0; i < 4; ++i) {
      float d0 = dot8(a0, a1, kva[i], kvb[i]);
      float d1 = dot8(b0, b1, kva[i], kvb[i]);
      d0 = fmaxf(d0 * scale, 0.f);
      d1 = fmaxf(d1 * scale, 0.f);
      r[i] = fmaf(w0, d0, fmaf(w1, d1, sb));
    }

    const int q = qb * 32 + lq;
    float* op = out + ((size_t)b * NN + q) * (size_t)NN + (size_t)(kb * 64 + k0);
    *(float4*)op = res;
  }
}

// ---------------------------------------------------------------------------
extern "C" void kernel_launch(void* const* d_in, const int* in_sizes, int n_in,
                              void* d_out, int out_size, void* d_ws, size_t ws_size,
                              hipStream_t stream) {
  const float* qt = (const float*)d_in[0];  // (2, 4096, 768)
  const float* kt = (const float*)d_in[1];  // (2, 4096, 768)
  const float* Wq = (const float*)d_in[2];  // (768, 18)
  const float* Wk = (const float*)d_in[3];  // (768, 8)
  const float* sb = (const float*)d_in[4];  // (1,1,1)
  const int* hp = (const int*)d_in[5];      // height (64)
  const int* wp = (const int*)d_in[6];      // width  (64)

  float* qd = (float*)d_ws;                      // 8192 * 20 floats = 640 KB
  float* kd = qd + (size_t)BB * NN * QSTRIDE;    // 8192 * 8 floats  = 256 KB
  float* outp = (float*)d_out;                   // (2, 4096, 4096) fp32

  // 8192 rows, 2 rows per wave, 4 waves per block -> 1024 blocks each
  qproj_kernel<<<BB * NN / 8, 256, 0, stream>>>(qt, Wq, qd);
  kproj_kernel<<<BB * NN / 8, 256, 0, stream>>>(kt, Wk, hp, wp, kd);
  // 64 key-tiles x 128 query-tiles x 2 batches
  scores_kernel<<<dim3(64, NN / 32, BB), 256, 0, stream>>>(qd, kd, sb, outp);
}

// Round 7
// 202.327 us; speedup vs baseline: 1.2720x; 1.2720x over previous
//
#include <hip/hip_runtime.h>
#include <math.h>

#define BB 2
#define NN 4096
#define DIM 768
#define QSTRIDE 20  // 8 (q head0) + 8 (q head1) + w0 + w1 + 2 pad, float4-aligned

typedef float f32x4 __attribute__((ext_vector_type(4)));

// ---------------------------------------------------------------------------
// qproj: qw = query_tokens @ Wq  (8192 rows x 768 -> 18 cols)
// One wave handles 2 rows. Lane-parallel over the 768 dim, butterfly reduce.
// Output layout per row (stride 20): [q0(8), q1(8), w0, w1, pad(2)]
//   qw cols: head0 q = 0..7, head0 w = 8, head1 q = 9..16, head1 w = 17
// (R0-proven kernel, unchanged.)
// ---------------------------------------------------------------------------
__global__ __launch_bounds__(256) void qproj_kernel(const float* __restrict__ x,
                                                    const float* __restrict__ Wq,
                                                    float* __restrict__ qd) {
  const int lane = threadIdx.x & 63;
  const int pair = blockIdx.x * 4 + (threadIdx.x >> 6);
  const int row0 = pair * 2;
  const float* xr0 = x + (size_t)row0 * DIM;
  const float* xr1 = xr0 + DIM;

  float acc0[18], acc1[18];
#pragma unroll
  for (int c = 0; c < 18; ++c) { acc0[c] = 0.f; acc1[c] = 0.f; }

#pragma unroll
  for (int j = 0; j < DIM / 64; ++j) {
    const int i = lane + 64 * j;
    const float x0 = xr0[i];
    const float x1 = xr1[i];
    const float* wr = Wq + i * 18;
#pragma unroll
    for (int c = 0; c < 9; ++c) {
      const float2 w2 = *(const float2*)(wr + 2 * c);
      acc0[2 * c]     = fmaf(x0, w2.x, acc0[2 * c]);
      acc0[2 * c + 1] = fmaf(x0, w2.y, acc0[2 * c + 1]);
      acc1[2 * c]     = fmaf(x1, w2.x, acc1[2 * c]);
      acc1[2 * c + 1] = fmaf(x1, w2.y, acc1[2 * c + 1]);
    }
  }

#pragma unroll
  for (int off = 32; off >= 1; off >>= 1) {
#pragma unroll
    for (int c = 0; c < 18; ++c) {
      acc0[c] += __shfl_xor(acc0[c], off, 64);
      acc1[c] += __shfl_xor(acc1[c], off, 64);
    }
  }

  // lanes 0..17 write row0, lanes 32..49 write row1 (all lanes hold full sums)
  const int r = lane >> 5;
  const int l = lane & 31;
  if (l < 18) {
    // dst slot l maps to qw column:
    //   l<8 -> col l ; 8<=l<16 -> col l+1 ; l==16 -> col 8 ; l==17 -> col 17
    int src;
    if (l < 8) src = l;
    else if (l < 16) src = l + 1;
    else if (l == 16) src = 8;
    else src = 17;
    float v = r ? acc1[0] : acc0[0];
#pragma unroll
    for (int c = 1; c < 18; ++c) {
      const float cand = r ? acc1[c] : acc0[c];
      v = (src == c) ? cand : v;
    }
    qd[(size_t)(row0 + r) * QSTRIDE + l] = v;
  }
}

// ---------------------------------------------------------------------------
// kproj: k = key_tokens @ Wk (8192 x 768 -> 8) + 2D sinusoidal PE
// pe[n] = [sin(y*h), cos(y*h), sin(y*.01h), cos(y*.01h),
//          sin(x*w), cos(x*w), sin(x*.01w), cos(x*.01w)]
//   y = (n/w_) / max(h-1,1), x = (n%w_) / max(w_-1,1); freqs = [1, 0.01]
// (R0-proven kernel, unchanged.)
// ---------------------------------------------------------------------------
__global__ __launch_bounds__(256) void kproj_kernel(const float* __restrict__ x,
                                                    const float* __restrict__ Wk,
                                                    const int* __restrict__ hp,
                                                    const int* __restrict__ wp,
                                                    float* __restrict__ kd) {
  const int lane = threadIdx.x & 63;
  const int pair = blockIdx.x * 4 + (threadIdx.x >> 6);
  const int row0 = pair * 2;
  const float* xr0 = x + (size_t)row0 * DIM;
  const float* xr1 = xr0 + DIM;

  float acc0[8], acc1[8];
#pragma unroll
  for (int c = 0; c < 8; ++c) { acc0[c] = 0.f; acc1[c] = 0.f; }

#pragma unroll
  for (int j = 0; j < DIM / 64; ++j) {
    const int i = lane + 64 * j;
    const float x0 = xr0[i];
    const float x1 = xr1[i];
    const float4 wa = *(const float4*)(Wk + i * 8);
    const float4 wb = *(const float4*)(Wk + i * 8 + 4);
    acc0[0] = fmaf(x0, wa.x, acc0[0]); acc0[1] = fmaf(x0, wa.y, acc0[1]);
    acc0[2] = fmaf(x0, wa.z, acc0[2]); acc0[3] = fmaf(x0, wa.w, acc0[3]);
    acc0[4] = fmaf(x0, wb.x, acc0[4]); acc0[5] = fmaf(x0, wb.y, acc0[5]);
    acc0[6] = fmaf(x0, wb.z, acc0[6]); acc0[7] = fmaf(x0, wb.w, acc0[7]);
    acc1[0] = fmaf(x1, wa.x, acc1[0]); acc1[1] = fmaf(x1, wa.y, acc1[1]);
    acc1[2] = fmaf(x1, wa.z, acc1[2]); acc1[3] = fmaf(x1, wa.w, acc1[3]);
    acc1[4] = fmaf(x1, wb.x, acc1[4]); acc1[5] = fmaf(x1, wb.y, acc1[5]);
    acc1[6] = fmaf(x1, wb.z, acc1[6]); acc1[7] = fmaf(x1, wb.w, acc1[7]);
  }

#pragma unroll
  for (int off = 32; off >= 1; off >>= 1) {
#pragma unroll
    for (int c = 0; c < 8; ++c) {
      acc0[c] += __shfl_xor(acc0[c], off, 64);
      acc1[c] += __shfl_xor(acc1[c], off, 64);
    }
  }

  const int r = lane >> 5;
  const int l = lane & 31;
  if (l < 8) {
    const int row = row0 + r;
    const int h = hp[0];
    const int w = wp[0];
    const int n = row % NN;
    const int yi = n / w;
    const int xi = n - yi * w;
    const int hd = (h - 1) > 1 ? (h - 1) : 1;
    const int wd = (w - 1) > 1 ? (w - 1) : 1;
    const float yv = (float)yi / (float)hd;
    const float xv = (float)xi / (float)wd;
    const float base = (l < 4) ? yv : xv;
    const float sc = (l < 4) ? (float)h : (float)w;
    const float fr = (l & 2) ? 0.01f : 1.0f;
    const float ang = base * fr * sc;
    const float pe = (l & 1) ? cosf(ang) : sinf(ang);
    float v = r ? acc1[0] : acc0[0];
#pragma unroll
    for (int c = 1; c < 8; ++c) {
      const float cand = r ? acc1[c] : acc0[c];
      v = (l == c) ? cand : v;
    }
    kd[(size_t)row * 8 + l] = v + pe;
  }
}

// ---------------------------------------------------------------------------
// scores: out[b,q,k] = w0*relu(scale*<q0,k>) + w1*relu(scale*<q1,k>) + bias
// Block: 256 threads; tile 32 queries x 64 keys (R0-proven geometry + LDS
// staging restored: R4 proved direct global loads are 2.5x slower — the
// kernel is VMEM-issue/latency bound, not BW bound; LDS amortizes it).
//
// NEW vs R0: k tile stored TRANSPOSED in LDS, ks[d][key]. Thread (tx,ty)
// reads its 4 keys for each d as ONE ds_read_b128 (banks (4tx..4tx+3)%32,
// 2 lanes/bank per wave = free, m136) -> kv fill is 8 b128 reads instead
// of 32 scalar b32 reads (b128 serves ~2x bytes/cycle, m134). Staging
// scatter: per write instr, 32 distinct keys -> 2 lanes/bank = free.
// Compute: 4 keys packed per f32x4, dot = 8 vector FMAs per head.
// q tile in LDS, stride 20 (b128-aligned, broadcast per ty-group).
// Stores: 2 float4 per thread, 256 B contiguous per tx-group (R0 pattern).
// ---------------------------------------------------------------------------
__global__ __launch_bounds__(256) void scores_kernel(const float* __restrict__ qd,
                                                     const float* __restrict__ kd,
                                                     const float* __restrict__ bias,
                                                     float* __restrict__ out) {
  __shared__ float ks[8][64];         // transposed k tile: ks[d][key], 2 KB
  __shared__ float qs[32 * QSTRIDE];  // 2.56 KB

  const int tid = threadIdx.x;
  const int kb = blockIdx.x;  // 64-key tile
  const int qb = blockIdx.y;  // 32-query tile
  const int b  = blockIdx.z;

  // stage k tile transposed: 64 keys x 8 floats = 128 float4 loads
  if (tid < 128) {
    const float4 v = ((const float4*)(kd + ((size_t)b * NN + kb * 64) * 8))[tid];
    const int key = tid >> 1;
    const int d0 = (tid & 1) * 4;
    ks[d0 + 0][key] = v.x;
    ks[d0 + 1][key] = v.y;
    ks[d0 + 2][key] = v.z;
    ks[d0 + 3][key] = v.w;
  }
  // stage q tile: 32 queries x 20 floats = 160 float4 loads, contiguous
  if (tid < 160) {
    ((float4*)qs)[tid] = ((const float4*)(qd + ((size_t)b * NN + qb * 32) * QSTRIDE))[tid];
  }
  __syncthreads();

  const int tx = tid & 15;
  const int ty = tid >> 4;
  const float sb = bias[0];
  const float scale = 0.35355339059327373f;  // 8^-0.5

  // kv: thread owns keys 4tx..4tx+3, one f32x4 per dim d
  const int k0 = tx * 4;
  f32x4 kvd[8];
#pragma unroll
  for (int d = 0; d < 8; ++d) kvd[d] = *(const f32x4*)(&ks[d][k0]);

#pragma unroll
  for (int qi = 0; qi < 2; ++qi) {
    const int lq = ty * 2 + qi;
    const float* qp = qs + lq * QSTRIDE;
    const float4 qa0 = *(const float4*)(qp);       // head0 q[0..3]
    const float4 qa1 = *(const float4*)(qp + 4);   // head0 q[4..7]
    const float4 qb0 = *(const float4*)(qp + 8);   // head1 q[0..3]
    const float4 qb1 = *(const float4*)(qp + 12);  // head1 q[4..7]
    const float w0 = qp[16];
    const float w1 = qp[17];

    // 4 keys at once: s = sum_d q[d] * kvd[d]  (fp-contract fuses to FMA)
    f32x4 s0 = qa0.x * kvd[0];
    f32x4 s1 = qb0.x * kvd[0];
    s0 += qa0.y * kvd[1];  s1 += qb0.y * kvd[1];
    s0 += qa0.z * kvd[2];  s1 += qb0.z * kvd[2];
    s0 += qa0.w * kvd[3];  s1 += qb0.w * kvd[3];
    s0 += qa1.x * kvd[4];  s1 += qb1.x * kvd[4];
    s0 += qa1.y * kvd[5];  s1 += qb1.y * kvd[5];
    s0 += qa1.z * kvd[6];  s1 += qb1.z * kvd[6];
    s0 += qa1.w * kvd[7];  s1 += qb1.w * kvd[7];

    f32x4 res;
#pragma unroll
    for (int i = 0; i < 4; ++i) {
      const float d0 = fmaxf(s0[i] * scale, 0.f);
      const float d1 = fmaxf(s1[i] * scale, 0.f);
      res[i] = fmaf(w0, d0, fmaf(w1, d1, sb));
    }

    const int q = qb * 32 + lq;
    float* op = out + ((size_t)b * NN + q) * (size_t)NN + (size_t)(kb * 64 + k0);
    *(f32x4*)op = res;
  }
}

// ---------------------------------------------------------------------------
extern "C" void kernel_launch(void* const* d_in, const int* in_sizes, int n_in,
                              void* d_out, int out_size, void* d_ws, size_t ws_size,
                              hipStream_t stream) {
  const float* qt = (const float*)d_in[0];  // (2, 4096, 768)
  const float* kt = (const float*)d_in[1];  // (2, 4096, 768)
  const float* Wq = (const float*)d_in[2];  // (768, 18)
  const float* Wk = (const float*)d_in[3];  // (768, 8)
  const float* sb = (const float*)d_in[4];  // (1,1,1)
  const int* hp = (const int*)d_in[5];      // height (64)
  const int* wp = (const int*)d_in[6];      // width  (64)

  float* qd = (float*)d_ws;                      // 8192 * 20 floats = 640 KB
  float* kd = qd + (size_t)BB * NN * QSTRIDE;    // 8192 * 8 floats  = 256 KB
  float* outp = (float*)d_out;                   // (2, 4096, 4096) fp32

  // 8192 rows, 2 rows per wave, 4 waves per block -> 1024 blocks each
  qproj_kernel<<<BB * NN / 8, 256, 0, stream>>>(qt, Wq, qd);
  kproj_kernel<<<BB * NN / 8, 256, 0, stream>>>(kt, Wk, hp, wp, kd);
  // 64 key-tiles x 128 query-tiles x 2 batches
  scores_kernel<<<dim3(64, NN / 32, BB), 256, 0, stream>>>(qd, kd, sb, outp);
}

// Round 8
// 200.711 us; speedup vs baseline: 1.2822x; 1.0081x over previous
//
#include <hip/hip_runtime.h>
#include <math.h>

#define BB 2
#define NN 4096
#define DIM 768
#define QSTRIDE 20  // 8 (q head0) + 8 (q head1) + w0 + w1 + 2 pad, float4-aligned
#define KT 128      // keys per scores block (clean retest: R2/R3 KT=128 were
                    // confounded with nt-stores / scalar strided stores)

typedef float f32x4 __attribute__((ext_vector_type(4)));

// ---------------------------------------------------------------------------
// qproj: qw = query_tokens @ Wq  (8192 rows x 768 -> 18 cols)
// One wave handles 2 rows. Lane-parallel over the 768 dim, butterfly reduce.
// Output layout per row (stride 20): [q0(8), q1(8), w0, w1, pad(2)]
//   qw cols: head0 q = 0..7, head0 w = 8, head1 q = 9..16, head1 w = 17
// (R0-proven kernel, unchanged.)
// ---------------------------------------------------------------------------
__global__ __launch_bounds__(256) void qproj_kernel(const float* __restrict__ x,
                                                    const float* __restrict__ Wq,
                                                    float* __restrict__ qd) {
  const int lane = threadIdx.x & 63;
  const int pair = blockIdx.x * 4 + (threadIdx.x >> 6);
  const int row0 = pair * 2;
  const float* xr0 = x + (size_t)row0 * DIM;
  const float* xr1 = xr0 + DIM;

  float acc0[18], acc1[18];
#pragma unroll
  for (int c = 0; c < 18; ++c) { acc0[c] = 0.f; acc1[c] = 0.f; }

#pragma unroll
  for (int j = 0; j < DIM / 64; ++j) {
    const int i = lane + 64 * j;
    const float x0 = xr0[i];
    const float x1 = xr1[i];
    const float* wr = Wq + i * 18;
#pragma unroll
    for (int c = 0; c < 9; ++c) {
      const float2 w2 = *(const float2*)(wr + 2 * c);
      acc0[2 * c]     = fmaf(x0, w2.x, acc0[2 * c]);
      acc0[2 * c + 1] = fmaf(x0, w2.y, acc0[2 * c + 1]);
      acc1[2 * c]     = fmaf(x1, w2.x, acc1[2 * c]);
      acc1[2 * c + 1] = fmaf(x1, w2.y, acc1[2 * c + 1]);
    }
  }

#pragma unroll
  for (int off = 32; off >= 1; off >>= 1) {
#pragma unroll
    for (int c = 0; c < 18; ++c) {
      acc0[c] += __shfl_xor(acc0[c], off, 64);
      acc1[c] += __shfl_xor(acc1[c], off, 64);
    }
  }

  // lanes 0..17 write row0, lanes 32..49 write row1 (all lanes hold full sums)
  const int r = lane >> 5;
  const int l = lane & 31;
  if (l < 18) {
    // dst slot l maps to qw column:
    //   l<8 -> col l ; 8<=l<16 -> col l+1 ; l==16 -> col 8 ; l==17 -> col 17
    int src;
    if (l < 8) src = l;
    else if (l < 16) src = l + 1;
    else if (l == 16) src = 8;
    else src = 17;
    float v = r ? acc1[0] : acc0[0];
#pragma unroll
    for (int c = 1; c < 18; ++c) {
      const float cand = r ? acc1[c] : acc0[c];
      v = (src == c) ? cand : v;
    }
    qd[(size_t)(row0 + r) * QSTRIDE + l] = v;
  }
}

// ---------------------------------------------------------------------------
// kproj: k = key_tokens @ Wk (8192 x 768 -> 8) + 2D sinusoidal PE
// pe[n] = [sin(y*h), cos(y*h), sin(y*.01h), cos(y*.01h),
//          sin(x*w), cos(x*w), sin(x*.01w), cos(x*.01w)]
//   y = (n/w_) / max(h-1,1), x = (n%w_) / max(w_-1,1); freqs = [1, 0.01]
// (R0-proven kernel, unchanged.)
// ---------------------------------------------------------------------------
__global__ __launch_bounds__(256) void kproj_kernel(const float* __restrict__ x,
                                                    const float* __restrict__ Wk,
                                                    const int* __restrict__ hp,
                                                    const int* __restrict__ wp,
                                                    float* __restrict__ kd) {
  const int lane = threadIdx.x & 63;
  const int pair = blockIdx.x * 4 + (threadIdx.x >> 6);
  const int row0 = pair * 2;
  const float* xr0 = x + (size_t)row0 * DIM;
  const float* xr1 = xr0 + DIM;

  float acc0[8], acc1[8];
#pragma unroll
  for (int c = 0; c < 8; ++c) { acc0[c] = 0.f; acc1[c] = 0.f; }

#pragma unroll
  for (int j = 0; j < DIM / 64; ++j) {
    const int i = lane + 64 * j;
    const float x0 = xr0[i];
    const float x1 = xr1[i];
    const float4 wa = *(const float4*)(Wk + i * 8);
    const float4 wb = *(const float4*)(Wk + i * 8 + 4);
    acc0[0] = fmaf(x0, wa.x, acc0[0]); acc0[1] = fmaf(x0, wa.y, acc0[1]);
    acc0[2] = fmaf(x0, wa.z, acc0[2]); acc0[3] = fmaf(x0, wa.w, acc0[3]);
    acc0[4] = fmaf(x0, wb.x, acc0[4]); acc0[5] = fmaf(x0, wb.y, acc0[5]);
    acc0[6] = fmaf(x0, wb.z, acc0[6]); acc0[7] = fmaf(x0, wb.w, acc0[7]);
    acc1[0] = fmaf(x1, wa.x, acc1[0]); acc1[1] = fmaf(x1, wa.y, acc1[1]);
    acc1[2] = fmaf(x1, wa.z, acc1[2]); acc1[3] = fmaf(x1, wa.w, acc1[3]);
    acc1[4] = fmaf(x1, wb.x, acc1[4]); acc1[5] = fmaf(x1, wb.y, acc1[5]);
    acc1[6] = fmaf(x1, wb.z, acc1[6]); acc1[7] = fmaf(x1, wb.w, acc1[7]);
  }

#pragma unroll
  for (int off = 32; off >= 1; off >>= 1) {
#pragma unroll
    for (int c = 0; c < 8; ++c) {
      acc0[c] += __shfl_xor(acc0[c], off, 64);
      acc1[c] += __shfl_xor(acc1[c], off, 64);
    }
  }

  const int r = lane >> 5;
  const int l = lane & 31;
  if (l < 8) {
    const int row = row0 + r;
    const int h = hp[0];
    const int w = wp[0];
    const int n = row % NN;
    const int yi = n / w;
    const int xi = n - yi * w;
    const int hd = (h - 1) > 1 ? (h - 1) : 1;
    const int wd = (w - 1) > 1 ? (w - 1) : 1;
    const float yv = (float)yi / (float)hd;
    const float xv = (float)xi / (float)wd;
    const float base = (l < 4) ? yv : xv;
    const float sc = (l < 4) ? (float)h : (float)w;
    const float fr = (l & 2) ? 0.01f : 1.0f;
    const float ang = base * fr * sc;
    const float pe = (l & 1) ? cosf(ang) : sinf(ang);
    float v = r ? acc1[0] : acc0[0];
#pragma unroll
    for (int c = 1; c < 8; ++c) {
      const float cand = r ? acc1[c] : acc0[c];
      v = (l == c) ? cand : v;
    }
    kd[(size_t)row * 8 + l] = v + pe;
  }
}

// ---------------------------------------------------------------------------
// scores: out[b,q,k] = w0*relu(scale*<q0,k>) + w1*relu(scale*<q1,k>) + bias
// Block: 256 threads; tile 32 queries x 128 keys. R7's transposed-k LDS +
// float4 stores kept; only geometry changes (2x work per block to amortize
// stage latency + barrier over twice the output; 8192 blocks vs 16384).
//
// k tile TRANSPOSED in LDS, ks[d][key]: kv fill reads 4 consecutive keys
// per ds_read_b128 at 16 B lane stride -> lanes 0-7 cover all 32 banks,
// lanes 8-15 repeat = 2 lanes/bank = free (m136). Staging uses all 256
// threads (1 float4 each), scatter 2 lanes/bank = free.
// Thread (tx,ty) owns keys {4tx..4tx+3} and {64+4tx..64+4tx+3}:
// 16 b128 kv reads, 2 float4 stores per query (256 B contiguous per
// tx-group). Per query: 32 packed f32x4 FMAs.
// ---------------------------------------------------------------------------
__global__ __launch_bounds__(256) void scores_kernel(const float* __restrict__ qd,
                                                     const float* __restrict__ kd,
                                                     const float* __restrict__ bias,
                                                     float* __restrict__ out) {
  __shared__ float ks[8][KT];         // transposed k tile: ks[d][key], 4 KB
  __shared__ float qs[32 * QSTRIDE];  // 2.56 KB

  const int tid = threadIdx.x;
  const int kb = blockIdx.x;  // 128-key tile
  const int qb = blockIdx.y;  // 32-query tile
  const int b  = blockIdx.z;

  // stage k tile transposed: 128 keys x 8 floats = 256 float4 loads
  {
    const float4 v = ((const float4*)(kd + ((size_t)b * NN + kb * KT) * 8))[tid];
    const int key = tid >> 1;
    const int d0 = (tid & 1) * 4;
    ks[d0 + 0][key] = v.x;
    ks[d0 + 1][key] = v.y;
    ks[d0 + 2][key] = v.z;
    ks[d0 + 3][key] = v.w;
  }
  // stage q tile: 32 queries x 20 floats = 160 float4 loads, contiguous
  if (tid < 160) {
    ((float4*)qs)[tid] = ((const float4*)(qd + ((size_t)b * NN + qb * 32) * QSTRIDE))[tid];
  }
  __syncthreads();

  const int tx = tid & 15;
  const int ty = tid >> 4;
  const float sb = bias[0];
  const float scale = 0.35355339059327373f;  // 8^-0.5

  // kv: thread owns key groups {4tx..4tx+3} and {64+4tx..64+4tx+3}
  const int k0 = tx * 4;
  f32x4 kvd0[8], kvd1[8];
#pragma unroll
  for (int d = 0; d < 8; ++d) {
    kvd0[d] = *(const f32x4*)(&ks[d][k0]);
    kvd1[d] = *(const f32x4*)(&ks[d][k0 + 64]);
  }

#pragma unroll
  for (int qi = 0; qi < 2; ++qi) {
    const int lq = ty * 2 + qi;
    const float* qp = qs + lq * QSTRIDE;
    const float4 qa0 = *(const float4*)(qp);       // head0 q[0..3]
    const float4 qa1 = *(const float4*)(qp + 4);   // head0 q[4..7]
    const float4 qb0 = *(const float4*)(qp + 8);   // head1 q[0..3]
    const float4 qb1 = *(const float4*)(qp + 12);  // head1 q[4..7]
    const float w0 = qp[16];
    const float w1 = qp[17];

    // 8 keys at once (two 4-wide groups): s = sum_d q[d] * kv[d]
    f32x4 s00 = qa0.x * kvd0[0];  f32x4 s01 = qa0.x * kvd1[0];
    f32x4 s10 = qb0.x * kvd0[0];  f32x4 s11 = qb0.x * kvd1[0];
    s00 += qa0.y * kvd0[1];  s01 += qa0.y * kvd1[1];
    s10 += qb0.y * kvd0[1];  s11 += qb0.y * kvd1[1];
    s00 += qa0.z * kvd0[2];  s01 += qa0.z * kvd1[2];
    s10 += qb0.z * kvd0[2];  s11 += qb0.z * kvd1[2];
    s00 += qa0.w * kvd0[3];  s01 += qa0.w * kvd1[3];
    s10 += qb0.w * kvd0[3];  s11 += qb0.w * kvd1[3];
    s00 += qa1.x * kvd0[4];  s01 += qa1.x * kvd1[4];
    s10 += qb1.x * kvd0[4];  s11 += qb1.x * kvd1[4];
    s00 += qa1.y * kvd0[5];  s01 += qa1.y * kvd1[5];
    s10 += qb1.y * kvd0[5];  s11 += qb1.y * kvd1[5];
    s00 += qa1.z * kvd0[6];  s01 += qa1.z * kvd1[6];
    s10 += qb1.z * kvd0[6];  s11 += qb1.z * kvd1[6];
    s00 += qa1.w * kvd0[7];  s01 += qa1.w * kvd1[7];
    s10 += qb1.w * kvd0[7];  s11 += qb1.w * kvd1[7];

    f32x4 res0, res1;
#pragma unroll
    for (int i = 0; i < 4; ++i) {
      const float d00 = fmaxf(s00[i] * scale, 0.f);
      const float d10 = fmaxf(s10[i] * scale, 0.f);
      res0[i] = fmaf(w0, d00, fmaf(w1, d10, sb));
      const float d01 = fmaxf(s01[i] * scale, 0.f);
      const float d11 = fmaxf(s11[i] * scale, 0.f);
      res1[i] = fmaf(w0, d01, fmaf(w1, d11, sb));
    }

    const int q = qb * 32 + lq;
    float* op = out + ((size_t)b * NN + q) * (size_t)NN + (size_t)(kb * KT + k0);
    *(f32x4*)op = res0;
    *(f32x4*)(op + 64) = res1;
  }
}

// ---------------------------------------------------------------------------
extern "C" void kernel_launch(void* const* d_in, const int* in_sizes, int n_in,
                              void* d_out, int out_size, void* d_ws, size_t ws_size,
                              hipStream_t stream) {
  const float* qt = (const float*)d_in[0];  // (2, 4096, 768)
  const float* kt = (const float*)d_in[1];  // (2, 4096, 768)
  const float* Wq = (const float*)d_in[2];  // (768, 18)
  const float* Wk = (const float*)d_in[3];  // (768, 8)
  const float* sb = (const float*)d_in[4];  // (1,1,1)
  const int* hp = (const int*)d_in[5];      // height (64)
  const int* wp = (const int*)d_in[6];      // width  (64)

  float* qd = (float*)d_ws;                      // 8192 * 20 floats = 640 KB
  float* kd = qd + (size_t)BB * NN * QSTRIDE;    // 8192 * 8 floats  = 256 KB
  float* outp = (float*)d_out;                   // (2, 4096, 4096) fp32

  // 8192 rows, 2 rows per wave, 4 waves per block -> 1024 blocks each
  qproj_kernel<<<BB * NN / 8, 256, 0, stream>>>(qt, Wq, qd);
  kproj_kernel<<<BB * NN / 8, 256, 0, stream>>>(kt, Wk, hp, wp, kd);
  // 32 key-tiles x 128 query-tiles x 2 batches
  scores_kernel<<<dim3(NN / KT, NN / 32, BB), 256, 0, stream>>>(qd, kd, sb, outp);
}